// Round 1
// baseline (60327.264 us; speedup 1.0000x reference)
//
#include <hip/hip_runtime.h>
#include <math.h>

#define T_LEN 1000
#define BATCH 16
#define MEL   80
#define HID   512
#define NCLS  64

__device__ __forceinline__ float fast_tanh(float x) {
    // robust: expf(+inf)->inf => 1-0=1 ; expf(-inf)->0 => -1
    float e = __expf(2.0f * x);
    return 1.0f - 2.0f / (e + 1.0f);
}
__device__ __forceinline__ float fast_sigmoid(float x) {
    return 1.0f / (1.0f + __expf(-x));
}

// K1: per (t): x_scale0/x_norm0 from feats, be0 = x_norm0 @ B0^T
__global__ __launch_bounds__(256) void k1_be0(const float* __restrict__ feats,
                                              const float* __restrict__ B0,
                                              float* __restrict__ be0) {
    const int t = blockIdx.x;
    const int tid = threadIdx.x;
    __shared__ float xf[BATCH][MEL];
    __shared__ float sc[BATCH];
    for (int idx = tid; idx < BATCH * MEL; idx += 256) {
        int b = idx / MEL, m = idx % MEL;
        xf[b][m] = feats[b * (T_LEN * MEL) + t * MEL + m];
    }
    __syncthreads();
    if (tid < BATCH) {
        float ss = 0.f;
        for (int m = 0; m < MEL; ++m) { float v = xf[tid][m]; ss += v * v; }
        sc[tid] = fmaxf(sqrtf(ss), 1e-6f);
    }
    __syncthreads();
    for (int idx = tid; idx < BATCH * MEL; idx += 256) {
        int b = idx / MEL, m = idx % MEL;
        float v = xf[b][m] / sc[b];
        xf[b][m] = fminf(fmaxf(v, -1.f), 1.f);
    }
    __syncthreads();
    for (int j = tid; j < HID; j += 256) {
        float acc[BATCH];
        #pragma unroll
        for (int b = 0; b < BATCH; ++b) acc[b] = 0.f;
        const float* brow = B0 + j * MEL;
        for (int k = 0; k < MEL; k += 4) {
            float4 w = *(const float4*)(brow + k);
            #pragma unroll
            for (int b = 0; b < BATCH; ++b) {
                float4 xv = *(const float4*)(&xf[b][k]);
                acc[b] += w.x * xv.x + w.y * xv.y + w.z * xv.z + w.w * xv.w;
            }
        }
        #pragma unroll
        for (int b = 0; b < BATCH; ++b)
            be0[(t * BATCH + b) * HID + j] = acc[b];
    }
}

// K2: per (t): x_scale1/x_norm1 from be0, be1 = x_norm1 @ B1^T, store xs1
__global__ __launch_bounds__(256) void k2_be1(const float* __restrict__ be0,
                                              const float* __restrict__ B1,
                                              float* __restrict__ be1,
                                              float* __restrict__ xs1) {
    const int t = blockIdx.x;
    const int tid = threadIdx.x;
    __shared__ float xn[BATCH][HID];
    __shared__ float sc[BATCH];
    __shared__ float psum[BATCH][16];
    for (int idx = tid; idx < BATCH * HID; idx += 256) {
        int b = idx >> 9, k = idx & 511;
        xn[b][k] = be0[(t * BATCH + b) * HID + k];
    }
    __syncthreads();
    {
        int b = tid >> 4, l = tid & 15;
        float ss = 0.f;
        for (int k = l; k < HID; k += 16) { float v = xn[b][k]; ss += v * v; }
        psum[b][l] = ss;
    }
    __syncthreads();
    if (tid < BATCH) {
        float ss = 0.f;
        #pragma unroll
        for (int l = 0; l < 16; ++l) ss += psum[tid][l];
        float s = fmaxf(sqrtf(ss), 1e-6f);
        sc[tid] = s;
        xs1[t * BATCH + tid] = s;
    }
    __syncthreads();
    for (int idx = tid; idx < BATCH * HID; idx += 256) {
        int b = idx >> 9, k = idx & 511;
        float v = xn[b][k] / sc[b];
        xn[b][k] = fminf(fmaxf(v, -1.f), 1.f);
    }
    __syncthreads();
    for (int j = tid; j < HID; j += 256) {
        float acc[BATCH];
        #pragma unroll
        for (int b = 0; b < BATCH; ++b) acc[b] = 0.f;
        const float* brow = B1 + j * HID;
        for (int k = 0; k < HID; k += 4) {
            float4 w = *(const float4*)(brow + k);
            #pragma unroll
            for (int b = 0; b < BATCH; ++b) {
                float4 xv = *(const float4*)(&xn[b][k]);
                acc[b] += w.x * xv.x + w.y * xv.y + w.z * xv.z + w.w * xv.w;
            }
        }
        #pragma unroll
        for (int b = 0; b < BATCH; ++b)
            be1[(t * BATCH + b) * HID + j] = acc[b];
    }
}

// K3: sequential h1 recurrence. One block per batch element.
__global__ __launch_bounds__(512) void k3_seq(const float* __restrict__ be0,
                                              const float* __restrict__ be1,
                                              const float* __restrict__ xs1,
                                              const float* __restrict__ C1,
                                              const float* __restrict__ W1,
                                              const float* __restrict__ a1,
                                              const float* __restrict__ tau,
                                              const float* __restrict__ gam,
                                              float* __restrict__ h1s) {
    const int b = blockIdx.x;
    const int j = threadIdx.x;
    __shared__ float h[HID];
    __shared__ float err[HID];
    __shared__ float red[8];
    __shared__ float s_surp;
    const float tauv = tau[0], gamv = gam[0];
    const float siga = fast_sigmoid(a1[j]);
    const float* c1row = C1 + j * HID;
    const float* w1row = W1 + j * HID;
    float hj = 0.f;
    h[j] = 0.f;
    __syncthreads();
    for (int t = 0; t < T_LEN; ++t) {
        const int row = (t * BATCH + b) * HID;
        // ---- matvec1: dp = (h @ C1^T)[j]
        float a0 = 0.f, a1v = 0.f, a2 = 0.f, a3 = 0.f;
        for (int k = 0; k < HID; k += 16) {
            float4 w0 = *(const float4*)(c1row + k);
            float4 w1 = *(const float4*)(c1row + k + 4);
            float4 w2 = *(const float4*)(c1row + k + 8);
            float4 w3 = *(const float4*)(c1row + k + 12);
            float4 h0 = *(const float4*)(h + k);
            float4 h1 = *(const float4*)(h + k + 4);
            float4 h2 = *(const float4*)(h + k + 8);
            float4 h3 = *(const float4*)(h + k + 12);
            a0 += w0.x * h0.x + w0.y * h0.y + w0.z * h0.z + w0.w * h0.w;
            a1v += w1.x * h1.x + w1.y * h1.y + w1.z * h1.z + w1.w * h1.w;
            a2 += w2.x * h2.x + w2.y * h2.y + w2.z * h2.z + w2.w * h2.w;
            a3 += w3.x * h3.x + w3.y * h3.y + w3.z * h3.z + w3.w * h3.w;
        }
        float dp = (a0 + a1v) + (a2 + a3);
        float p = fast_tanh(dp);
        float xs = xs1[t * BATCH + b];
        float e = be0[row + j] - p * xs;
        err[j] = e;
        float part = e * e;
        #pragma unroll
        for (int off = 32; off > 0; off >>= 1) part += __shfl_down(part, off, 64);
        if ((j & 63) == 0) red[j >> 6] = part;
        __syncthreads();  // (A) err[] complete, wave partials in red[]
        if (j == 0) {
            float ss = 0.f;
            #pragma unroll
            for (int w = 0; w < 8; ++w) ss += red[w];
            float rel = fminf(sqrtf(ss) / xs, 4.0f);
            s_surp = fast_sigmoid((rel - tauv) / gamv);
        }
        __syncthreads();  // (B) surprise scalar ready
        const float s = s_surp;
        // ---- matvec2: ee = (error @ W1^T)[j]
        float c0 = 0.f, c1 = 0.f, c2 = 0.f, c3 = 0.f;
        for (int k = 0; k < HID; k += 16) {
            float4 w0 = *(const float4*)(w1row + k);
            float4 w1 = *(const float4*)(w1row + k + 4);
            float4 w2 = *(const float4*)(w1row + k + 8);
            float4 w3 = *(const float4*)(w1row + k + 12);
            float4 e0 = *(const float4*)(err + k);
            float4 e1 = *(const float4*)(err + k + 4);
            float4 e2 = *(const float4*)(err + k + 8);
            float4 e3 = *(const float4*)(err + k + 12);
            c0 += w0.x * e0.x + w0.y * e0.y + w0.z * e0.z + w0.w * e0.w;
            c1 += w1.x * e1.x + w1.y * e1.y + w1.z * e1.z + w1.w * e1.w;
            c2 += w2.x * e2.x + w2.y * e2.y + w2.z * e2.z + w2.w * e2.w;
            c3 += w3.x * e3.x + w3.y * e3.y + w3.z * e3.z + w3.w * e3.w;
        }
        float ee = (c0 + c1) + (c2 + c3);
        float be1v = be1[row + j];
        float input_h = hj * 0.2f + be1v * 0.6f + ee * s * 0.2f;
        float g = s * siga;
        hj = hj * (1.f - g) + fast_tanh(input_h) * g;
        h[j] = hj;
        h1s[row + j] = hj;
        __syncthreads();  // (C) h[] updated for next step
    }
}

// K4: head matmul out[b,t,c] = [h1 || be1] @ head_w^T + head_b
__global__ __launch_bounds__(1024) void k4_head(const float* __restrict__ h1s,
                                                const float* __restrict__ be1,
                                                const float* __restrict__ head_w,
                                                const float* __restrict__ head_b,
                                                float* __restrict__ out) {
    const int t = blockIdx.x;
    const int tid = threadIdx.x;
    const int c = tid >> 4;   // 0..63
    const int b = tid & 15;   // 0..15
    const float* hw = head_w + c * (2 * HID);
    const float* x1 = h1s + (size_t)(t * BATCH + b) * HID;
    const float* x2 = be1 + (size_t)(t * BATCH + b) * HID;
    float acc0 = head_b[c], acc1 = 0.f;
    for (int k = 0; k < HID; k += 4) {
        float4 w = *(const float4*)(hw + k);
        float4 xv = *(const float4*)(x1 + k);
        acc0 += w.x * xv.x + w.y * xv.y + w.z * xv.z + w.w * xv.w;
    }
    for (int k = 0; k < HID; k += 4) {
        float4 w = *(const float4*)(hw + HID + k);
        float4 xv = *(const float4*)(x2 + k);
        acc1 += w.x * xv.x + w.y * xv.y + w.z * xv.z + w.w * xv.w;
    }
    out[b * (T_LEN * NCLS) + t * NCLS + c] = acc0 + acc1;
}

extern "C" void kernel_launch(void* const* d_in, const int* in_sizes, int n_in,
                              void* d_out, int out_size, void* d_ws, size_t ws_size,
                              hipStream_t stream) {
    const float* feats  = (const float*)d_in[0];
    const float* B0     = (const float*)d_in[2];
    const float* C1     = (const float*)d_in[7];
    const float* B1     = (const float*)d_in[8];
    const float* W1     = (const float*)d_in[9];
    const float* a1     = (const float*)d_in[10];
    const float* tau1   = (const float*)d_in[11];
    const float* gam1   = (const float*)d_in[12];
    const float* head_w = (const float*)d_in[13];
    const float* head_b = (const float*)d_in[14];
    float* out = (float*)d_out;

    float* be0 = (float*)d_ws;                         // T*B*HID
    float* be1 = be0 + (size_t)T_LEN * BATCH * HID;    // T*B*HID
    float* xs1 = be1 + (size_t)T_LEN * BATCH * HID;    // T*B
    float* h1s = xs1 + (size_t)T_LEN * BATCH;          // T*B*HID

    hipLaunchKernelGGL(k1_be0, dim3(T_LEN), dim3(256), 0, stream, feats, B0, be0);
    hipLaunchKernelGGL(k2_be1, dim3(T_LEN), dim3(256), 0, stream, be0, B1, be1, xs1);
    hipLaunchKernelGGL(k3_seq, dim3(BATCH), dim3(512), 0, stream,
                       be0, be1, xs1, C1, W1, a1, tau1, gam1, h1s);
    hipLaunchKernelGGL(k4_head, dim3(T_LEN), dim3(1024), 0, stream,
                       h1s, be1, head_w, head_b, out);
}